// Round 17
// baseline (260.896 us; speedup 1.0000x reference)
//
#include <hip/hip_runtime.h>
#include <hip/hip_bf16.h>

typedef unsigned int uint32;

#define BATCH 32
#define NIN   2048
#define DIN   16
#define NCAP  64
#define DCAP  32
#define ROW   2048   // NCAP*DCAP

__device__ __forceinline__ uint32 pack_bf2(float a, float b){
    union { __hip_bfloat16 h; ushort u; } ca, cb;
    ca.h = __float2bfloat16(a);
    cb.h = __float2bfloat16(b);
    return (uint32)ca.u | ((uint32)cb.u << 16);
}
__device__ __forceinline__ float bf_lo(uint32 w){ return __uint_as_float(w << 16); }
__device__ __forceinline__ float bf_hi(uint32 w){ return __uint_as_float(w & 0xffff0000u); }

// ---------------------------------------------------------------------------
// K1 (R16 winner + merged ce-halves): one 512-thread block per chunk covers
// all 64 caps -> whole 4KB u-rows written by one CU, single x-staging.
//     u[n][b][c*32+e] = sum_d x[b,n,d]*W[n,c,d,e] + B[c,e]   (bf16, R16 win)
//     part[b][chunk][ce] = sum_{n in chunk} u  (bf16, [b][ch] for k2 locality)
// grid = (256 chunks of 8 n), block 512; thread owns (c, 4 e's) x 32 b.
// ---------------------------------------------------------------------------
__global__ __launch_bounds__(512, 1)
void k1_predict(const float* __restrict__ x, const float* __restrict__ W,
                const float* __restrict__ Bc, __hip_bfloat16* __restrict__ u,
                ushort* __restrict__ part)
{
    __shared__ float xs[8 * 32 * 16];               // [i][b][d], 16 KB
    const int t     = threadIdx.x;                  // 0..511
    const int chunk = blockIdx.x;                   // 0..255, 8 n each
    const int n0    = chunk * 8;
    const int cg    = t >> 3;                       // 0..63 capsule
    const int e0    = (t & 7) * 4;                  // 4 consecutive e

    #pragma unroll
    for (int k = 0; k < 2; ++k) {
        const int f = (t + 512 * k) * 4;
        const int i = f >> 9, rem = f & 511, b = rem >> 4, d = rem & 15;
        *(float4*)(xs + f) = *(const float4*)(x + ((size_t)b * NIN + n0 + i) * DIN + d);
    }
    __syncthreads();

    const float4 bias = *(const float4*)(Bc + cg * DCAP + e0);

    float sacc[32][4];
    #pragma unroll
    for (int b = 0; b < 32; ++b) {
        sacc[b][0] = 0.f; sacc[b][1] = 0.f; sacc[b][2] = 0.f; sacc[b][3] = 0.f;
    }

    const float* wbase = W + (size_t)cg * (DIN * DCAP) + e0;
    for (int i = 0; i < 8; ++i) {
        const int n = n0 + i;
        float4 w[16];
        {
            const float* wp = wbase + (size_t)n * (NCAP * DIN * DCAP);
            #pragma unroll
            for (int d = 0; d < 16; ++d) w[d] = *(const float4*)(wp + d * DCAP);
        }
        const float* xrow = xs + i * 512;
        // u layout [n][b][ce]: per-b stride = ROW (4KB) — R16-proven locality win
        __hip_bfloat16* ub = u + (size_t)n * (BATCH * ROW) + cg * DCAP + e0;

        #pragma unroll
        for (int b = 0; b < 32; ++b) {
            float4 uv = bias;
            #pragma unroll
            for (int d4 = 0; d4 < 4; ++d4) {
                const float4 xv = *(const float4*)(xrow + b * 16 + d4 * 4);  // broadcast
                uv.x = fmaf(xv.x, w[d4*4+0].x, uv.x);
                uv.y = fmaf(xv.x, w[d4*4+0].y, uv.y);
                uv.z = fmaf(xv.x, w[d4*4+0].z, uv.z);
                uv.w = fmaf(xv.x, w[d4*4+0].w, uv.w);
                uv.x = fmaf(xv.y, w[d4*4+1].x, uv.x);
                uv.y = fmaf(xv.y, w[d4*4+1].y, uv.y);
                uv.z = fmaf(xv.y, w[d4*4+1].z, uv.z);
                uv.w = fmaf(xv.y, w[d4*4+1].w, uv.w);
                uv.x = fmaf(xv.z, w[d4*4+2].x, uv.x);
                uv.y = fmaf(xv.z, w[d4*4+2].y, uv.y);
                uv.z = fmaf(xv.z, w[d4*4+2].z, uv.z);
                uv.w = fmaf(xv.z, w[d4*4+2].w, uv.w);
                uv.x = fmaf(xv.w, w[d4*4+3].x, uv.x);
                uv.y = fmaf(xv.w, w[d4*4+3].y, uv.y);
                uv.z = fmaf(xv.w, w[d4*4+3].z, uv.z);
                uv.w = fmaf(xv.w, w[d4*4+3].w, uv.w);
            }
            sacc[b][0] += uv.x; sacc[b][1] += uv.y;
            sacc[b][2] += uv.z; sacc[b][3] += uv.w;
            uint2 pk;
            pk.x = pack_bf2(uv.x, uv.y);
            pk.y = pack_bf2(uv.z, uv.w);
            *(uint2*)(ub + (size_t)b * ROW) = pk;
        }
    }

    // part layout [b][chunk][ce] (k2#1 reads at 4KB stride per ch)
    #pragma unroll
    for (int b = 0; b < 32; ++b) {
        uint2 pk;
        pk.x = pack_bf2(sacc[b][0], sacc[b][1]);
        pk.y = pack_bf2(sacc[b][2], sacc[b][3]);
        *(uint2*)(part + ((size_t)b * 256 + chunk) * ROW + cg * DCAP + e0) = pk;
    }
}

// ---------------------------------------------------------------------------
// K2: s[b,p0..p0+3] = factor * sum_ch part[b][ch][p]; v = squash(s);
//     V = (first ? v : V+v); if(out) out = v.  part bf16 or f32 per flag.
// grid = (8, BATCH), block 64; thread owns 4 consecutive p (e-group = 8 lanes)
// ---------------------------------------------------------------------------
__global__ __launch_bounds__(64)
void k2_squash(const void* __restrict__ partv, int nch, int isbf16, float factor,
               float* __restrict__ V, float* __restrict__ out, int first)
{
    const int t  = threadIdx.x;
    const int b  = blockIdx.y;
    const int p0 = (blockIdx.x * 64 + t) * 4;

    float a0 = 0.f, a1 = 0.f, a2 = 0.f, a3 = 0.f;
    if (isbf16) {
        const ushort* pp = (const ushort*)partv;
        #pragma unroll 4
        for (int ch = 0; ch < nch; ++ch) {
            const uint2 v = *(const uint2*)(pp + ((size_t)b * nch + ch) * ROW + p0);
            a0 += bf_lo(v.x); a1 += bf_hi(v.x);
            a2 += bf_lo(v.y); a3 += bf_hi(v.y);
        }
    } else {
        const float* pp = (const float*)partv;
        #pragma unroll 4
        for (int ch = 0; ch < nch; ++ch) {
            const float4 v = *(const float4*)(pp + ((size_t)b * nch + ch) * ROW + p0);
            a0 += v.x; a1 += v.y; a2 += v.z; a3 += v.w;
        }
    }
    a0 *= factor; a1 *= factor; a2 *= factor; a3 *= factor;

    float nsq = a0*a0 + a1*a1 + a2*a2 + a3*a3;
    nsq += __shfl_xor(nsq, 1);
    nsq += __shfl_xor(nsq, 2);
    nsq += __shfl_xor(nsq, 4);                       // 8 lanes × 4 = 32 e
    const float scale = nsq / ((1.f + nsq) * sqrtf(nsq + 1e-9f));
    const float v0 = scale*a0, v1 = scale*a1, v2 = scale*a2, v3 = scale*a3;

    const size_t idx = (size_t)b * ROW + p0;
    float4 Vn;
    if (first) Vn = make_float4(v0, v1, v2, v3);
    else {
        const float4 old = *(const float4*)(V + idx);
        Vn = make_float4(old.x+v0, old.y+v1, old.z+v2, old.w+v3);
    }
    *(float4*)(V + idx) = Vn;
    if (out) *(float4*)(out + idx) = make_float4(v0, v1, v2, v3);
}

// ---------------------------------------------------------------------------
// K3 sweep, COALESCED (R16-proven, unchanged): u rows at n*BATCH+b; wave
// reads row contiguously; lane holds e-slice es=(l&3)*8 of capsules
// q*16+(l>>2). Quad-shfl logit reduce, wave softmax denom (*4), no max-sub.
// 4-wave blocks, LDS c*33+e reduce, f32 partials [b][32chunks].
// grid = (32 n-chunks of 64, BATCH), block 256.
// ---------------------------------------------------------------------------
__global__ __launch_bounds__(256)
void k3_sweep(const __hip_bfloat16* __restrict__ u, const float* __restrict__ V,
              float* __restrict__ part)
{
    __shared__ float red[4 * 2112];                  // [wave][c*33+e]
    const int t     = threadIdx.x;
    const int lane  = t & 63;
    const int wv    = t >> 6;
    const int chunk = blockIdx.x;
    const int b     = blockIdx.y;

    const int qr = lane >> 2;                        // 0..15: capsule-in-quarter
    const int es = (lane & 3) * 8;                   // e-slice start

    float vr[4][8];
    #pragma unroll
    for (int q = 0; q < 4; ++q) {
        const float* vp = V + (size_t)b * ROW + (q * 16 + qr) * DCAP + es;
        const float4 v0 = *(const float4*)(vp);
        const float4 v1 = *(const float4*)(vp + 4);
        vr[q][0]=v0.x; vr[q][1]=v0.y; vr[q][2]=v0.z; vr[q][3]=v0.w;
        vr[q][4]=v1.x; vr[q][5]=v1.y; vr[q][6]=v1.z; vr[q][7]=v1.w;
    }

    float sacc[4][8];
    #pragma unroll
    for (int q = 0; q < 4; ++q)
        #pragma unroll
        for (int j = 0; j < 8; ++j) sacc[q][j] = 0.f;

    const int nbase = chunk * 64 + wv * 16;
    // u row = n*BATCH + b ; per-n stride = BATCH*ROW
    const __hip_bfloat16* ubase = u + ((size_t)nbase * BATCH + b) * ROW + lane * 8;

    uint4 A[4];
    #pragma unroll
    for (int q = 0; q < 4; ++q)
        A[q] = *(const uint4*)(ubase + q * 512);

    for (int it = 0; it < 16; ++it) {
        uint4 Bn[4];
        if (it < 15) {
            const __hip_bfloat16* un = ubase + (size_t)(it + 1) * (BATCH * ROW);
            #pragma unroll
            for (int q = 0; q < 4; ++q)
                Bn[q] = *(const uint4*)(un + q * 512);
        }

        float p[4];
        #pragma unroll
        for (int q = 0; q < 4; ++q) {
            const uint32 w0 = A[q].x, w1 = A[q].y, w2 = A[q].z, w3 = A[q].w;
            float l0 = bf_lo(w0) * vr[q][0];
            float l1 = bf_hi(w0) * vr[q][1];
            l0 = fmaf(bf_lo(w1), vr[q][2], l0);
            l1 = fmaf(bf_hi(w1), vr[q][3], l1);
            l0 = fmaf(bf_lo(w2), vr[q][4], l0);
            l1 = fmaf(bf_hi(w2), vr[q][5], l1);
            l0 = fmaf(bf_lo(w3), vr[q][6], l0);
            l1 = fmaf(bf_hi(w3), vr[q][7], l1);
            p[q] = l0 + l1;
        }
        #pragma unroll
        for (int q = 0; q < 4; ++q) {
            p[q] += __shfl_xor(p[q], 1);
            p[q] += __shfl_xor(p[q], 2);
        }
        float e0 = __expf(p[0]), e1 = __expf(p[1]),
              e2 = __expf(p[2]), e3 = __expf(p[3]);
        float s = (e0 + e1) + (e2 + e3);
        s += __shfl_xor(s, 4);
        s += __shfl_xor(s, 8);
        s += __shfl_xor(s, 16);
        s += __shfl_xor(s, 32);                      // s = 4 * sum_c exp
        const float inv = 4.0f / s;
        const float cw[4] = {e0 * inv, e1 * inv, e2 * inv, e3 * inv};

        #pragma unroll
        for (int q = 0; q < 4; ++q) {
            const uint32 w0 = A[q].x, w1 = A[q].y, w2 = A[q].z, w3 = A[q].w;
            const float c = cw[q];
            sacc[q][0] = fmaf(c, bf_lo(w0), sacc[q][0]);
            sacc[q][1] = fmaf(c, bf_hi(w0), sacc[q][1]);
            sacc[q][2] = fmaf(c, bf_lo(w1), sacc[q][2]);
            sacc[q][3] = fmaf(c, bf_hi(w1), sacc[q][3]);
            sacc[q][4] = fmaf(c, bf_lo(w2), sacc[q][4]);
            sacc[q][5] = fmaf(c, bf_hi(w2), sacc[q][5]);
            sacc[q][6] = fmaf(c, bf_lo(w3), sacc[q][6]);
            sacc[q][7] = fmaf(c, bf_hi(w3), sacc[q][7]);
        }

        if (it < 15) {
            #pragma unroll
            for (int q = 0; q < 4; ++q) A[q] = Bn[q];
        }
    }

    #pragma unroll
    for (int q = 0; q < 4; ++q) {
        const int c = q * 16 + qr;
        #pragma unroll
        for (int j = 0; j < 8; ++j)
            red[wv * 2112 + c * 33 + es + j] = sacc[q][j];
    }
    __syncthreads();
    #pragma unroll
    for (int k = 0; k < 8; ++k) {
        const int pp = t + 256 * k;
        const int c = pp >> 5, e = pp & 31;
        part[((size_t)b * 32 + chunk) * ROW + pp] =
            red[0*2112 + c*33+e] + red[1*2112 + c*33+e] +
            red[2*2112 + c*33+e] + red[3*2112 + c*33+e];
    }
}

// ---------------------------------------------------------------------------
extern "C" void kernel_launch(void* const* d_in, const int* in_sizes, int n_in,
                              void* d_out, int out_size, void* d_ws, size_t ws_size,
                              hipStream_t stream)
{
    const float* x  = (const float*)d_in[0];
    const float* W  = (const float*)d_in[1];
    const float* Bc = (const float*)d_in[2];
    float* out = (float*)d_out;

    const size_t off_u    = 0;                       // u: 32*2048*2048 bf16 = 256 MiB
    const size_t off_part = 268435456;               // part: 32 MiB max
    const size_t off_V    = off_part + 33554432;     // V: 32*64*32 f32
    const size_t need     = off_V + 262144;
    if (ws_size < need) return;

    __hip_bfloat16* u  = (__hip_bfloat16*)((char*)d_ws + off_u);
    ushort* part_bf    = (ushort*)((char*)d_ws + off_part);
    float*  part_f     = (float*)((char*)d_ws + off_part);   // aliased: consumed before k3 writes
    float*  V          = (float*)((char*)d_ws + off_V);

    // iter 1: u + uniform-softmax s1 fused (bf16 partials)
    k1_predict<<<dim3(256), 512, 0, stream>>>(x, W, Bc, u, part_bf);
    k2_squash <<<dim3(8, BATCH), 64, 0, stream>>>(part_bf, 256, 1, 1.0f/64.0f, V, nullptr, 1);
    // iter 2: logits = u.V (V=v1), softmax, s2
    k3_sweep  <<<dim3(32, BATCH), 256, 0, stream>>>(u, V, part_f);
    k2_squash <<<dim3(8, BATCH), 64, 0, stream>>>(part_f, 32, 0, 1.0f, V, nullptr, 0);
    // iter 3: logits = u.(v1+v2), softmax, s3 -> v3 = output
    k3_sweep  <<<dim3(32, BATCH), 256, 0, stream>>>(u, V, part_f);
    k2_squash <<<dim3(8, BATCH), 64, 0, stream>>>(part_f, 32, 0, 1.0f, V, out, 0);
}

// Round 18
// 249.609 us; speedup vs baseline: 1.0452x; 1.0452x over previous
//
#include <hip/hip_runtime.h>
#include <hip/hip_bf16.h>

typedef unsigned int uint32;

#define BATCH 32
#define NIN   2048
#define DIN   16
#define NCAP  64
#define DCAP  32
#define ROW   2048   // NCAP*DCAP

__device__ __forceinline__ uint32 pack_bf2(float a, float b){
    union { __hip_bfloat16 h; ushort u; } ca, cb;
    ca.h = __float2bfloat16(a);
    cb.h = __float2bfloat16(b);
    return (uint32)ca.u | ((uint32)cb.u << 16);
}
__device__ __forceinline__ float bf_lo(uint32 w){ return __uint_as_float(w << 16); }
__device__ __forceinline__ float bf_hi(uint32 w){ return __uint_as_float(w & 0xffff0000u); }

// ---------------------------------------------------------------------------
// K1 (R16 winner, session best 249.6us): R5 shape + u relayout [n][b][ce] —
// per (n) step the 32 per-b stores land 4KB apart (128KB window) instead of
// 8MB apart -> DRAM row / L2-WB locality (-14us, the only k1 lever that paid
// out of 11 tried). R17's 512-block merge regressed (-11us) — keep 2x256.
//     u[n][b][c*32+e] = sum_d x[b,n,d]*W[n,c,d,e] + B[c,e]   (bf16)
//     part[chunk][b][ce] = sum_{n in chunk} u                (bf16)
// grid = (2 ce-halves, 256 chunks of 8 n), block 256; thread owns (c, 4 e's).
// ---------------------------------------------------------------------------
__global__ __launch_bounds__(256, 2)
void k1_predict(const float* __restrict__ x, const float* __restrict__ W,
                const float* __restrict__ Bc, __hip_bfloat16* __restrict__ u,
                ushort* __restrict__ part)
{
    __shared__ float xs[8 * 32 * 16];               // [i][b][d], 16 KB
    const int t     = threadIdx.x;
    const int half  = blockIdx.x;                   // ce-half
    const int chunk = blockIdx.y;                   // 0..255, 8 n each
    const int n0    = chunk * 8;
    const int cl    = t >> 3;                       // 0..31 local capsule
    const int e0    = (t & 7) * 4;                  // 4 consecutive e
    const int cg    = half * 32 + cl;               // global capsule

    #pragma unroll
    for (int k = 0; k < 4; ++k) {
        const int f = (t + 256 * k) * 4;
        const int i = f >> 9, rem = f & 511, b = rem >> 4, d = rem & 15;
        *(float4*)(xs + f) = *(const float4*)(x + ((size_t)b * NIN + n0 + i) * DIN + d);
    }
    __syncthreads();

    const float4 bias = *(const float4*)(Bc + cg * DCAP + e0);

    float sacc[32][4];
    #pragma unroll
    for (int b = 0; b < 32; ++b) {
        sacc[b][0] = 0.f; sacc[b][1] = 0.f; sacc[b][2] = 0.f; sacc[b][3] = 0.f;
    }

    const float* wbase = W + (size_t)cg * (DIN * DCAP) + e0;
    for (int i = 0; i < 8; ++i) {
        const int n = n0 + i;
        float4 w[16];
        {
            const float* wp = wbase + (size_t)n * (NCAP * DIN * DCAP);
            #pragma unroll
            for (int d = 0; d < 16; ++d) w[d] = *(const float4*)(wp + d * DCAP);
        }
        const float* xrow = xs + i * 512;
        // u relayout: row = n*BATCH + b  -> per-b stride is ROW (4KB)
        __hip_bfloat16* ub = u + (size_t)n * (BATCH * ROW) + cg * DCAP + e0;

        #pragma unroll
        for (int b = 0; b < 32; ++b) {
            float4 uv = bias;
            #pragma unroll
            for (int d4 = 0; d4 < 4; ++d4) {
                const float4 xv = *(const float4*)(xrow + b * 16 + d4 * 4);  // broadcast
                uv.x = fmaf(xv.x, w[d4*4+0].x, uv.x);
                uv.y = fmaf(xv.x, w[d4*4+0].y, uv.y);
                uv.z = fmaf(xv.x, w[d4*4+0].z, uv.z);
                uv.w = fmaf(xv.x, w[d4*4+0].w, uv.w);
                uv.x = fmaf(xv.y, w[d4*4+1].x, uv.x);
                uv.y = fmaf(xv.y, w[d4*4+1].y, uv.y);
                uv.z = fmaf(xv.y, w[d4*4+1].z, uv.z);
                uv.w = fmaf(xv.y, w[d4*4+1].w, uv.w);
                uv.x = fmaf(xv.z, w[d4*4+2].x, uv.x);
                uv.y = fmaf(xv.z, w[d4*4+2].y, uv.y);
                uv.z = fmaf(xv.z, w[d4*4+2].z, uv.z);
                uv.w = fmaf(xv.z, w[d4*4+2].w, uv.w);
                uv.x = fmaf(xv.w, w[d4*4+3].x, uv.x);
                uv.y = fmaf(xv.w, w[d4*4+3].y, uv.y);
                uv.z = fmaf(xv.w, w[d4*4+3].z, uv.z);
                uv.w = fmaf(xv.w, w[d4*4+3].w, uv.w);
            }
            sacc[b][0] += uv.x; sacc[b][1] += uv.y;
            sacc[b][2] += uv.z; sacc[b][3] += uv.w;
            uint2 pk;
            pk.x = pack_bf2(uv.x, uv.y);
            pk.y = pack_bf2(uv.z, uv.w);
            *(uint2*)(ub + (size_t)b * ROW) = pk;
        }
    }

    // part relayout: row = chunk*BATCH + b -> per-b stride is ROW (4KB)
    ushort* pb = part + (size_t)chunk * (BATCH * ROW) + cg * DCAP + e0;
    #pragma unroll
    for (int b = 0; b < 32; ++b) {
        uint2 pk;
        pk.x = pack_bf2(sacc[b][0], sacc[b][1]);
        pk.y = pack_bf2(sacc[b][2], sacc[b][3]);
        *(uint2*)(pb + (size_t)b * ROW) = pk;
    }
}

// ---------------------------------------------------------------------------
// K2: s[b,p0..p0+3] = factor * sum_ch part[..]; v = squash(s);
//     V = (first ? v : V+v); if(out) out = v.
// bf16 path indexes part as [ch][b][p] (k1's layout);
// f32  path indexes part as [b][ch][p] (k3's layout).
// grid = (8, BATCH), block 64; thread owns 4 consecutive p (e-group = 8 lanes)
// ---------------------------------------------------------------------------
__global__ __launch_bounds__(64)
void k2_squash(const void* __restrict__ partv, int nch, int isbf16, float factor,
               float* __restrict__ V, float* __restrict__ out, int first)
{
    const int t  = threadIdx.x;
    const int b  = blockIdx.y;
    const int p0 = (blockIdx.x * 64 + t) * 4;

    float a0 = 0.f, a1 = 0.f, a2 = 0.f, a3 = 0.f;
    if (isbf16) {
        const ushort* pp = (const ushort*)partv;
        #pragma unroll 4
        for (int ch = 0; ch < nch; ++ch) {
            const uint2 v = *(const uint2*)(pp + ((size_t)ch * BATCH + b) * ROW + p0);
            a0 += bf_lo(v.x); a1 += bf_hi(v.x);
            a2 += bf_lo(v.y); a3 += bf_hi(v.y);
        }
    } else {
        const float* pp = (const float*)partv;
        #pragma unroll 4
        for (int ch = 0; ch < nch; ++ch) {
            const float4 v = *(const float4*)(pp + ((size_t)b * nch + ch) * ROW + p0);
            a0 += v.x; a1 += v.y; a2 += v.z; a3 += v.w;
        }
    }
    a0 *= factor; a1 *= factor; a2 *= factor; a3 *= factor;

    float nsq = a0*a0 + a1*a1 + a2*a2 + a3*a3;
    nsq += __shfl_xor(nsq, 1);
    nsq += __shfl_xor(nsq, 2);
    nsq += __shfl_xor(nsq, 4);                       // 8 lanes × 4 = 32 e
    const float scale = nsq / ((1.f + nsq) * sqrtf(nsq + 1e-9f));
    const float v0 = scale*a0, v1 = scale*a1, v2 = scale*a2, v3 = scale*a3;

    const size_t idx = (size_t)b * ROW + p0;
    float4 Vn;
    if (first) Vn = make_float4(v0, v1, v2, v3);
    else {
        const float4 old = *(const float4*)(V + idx);
        Vn = make_float4(old.x+v0, old.y+v1, old.z+v2, old.w+v3);
    }
    *(float4*)(V + idx) = Vn;
    if (out) *(float4*)(out + idx) = make_float4(v0, v1, v2, v3);
}

// ---------------------------------------------------------------------------
// K3 sweep, COALESCED (R16-proven): u rows at n*BATCH+b; wave reads row
// contiguously; lane holds e-slice es=(l&3)*8 of capsules q*16+(l>>2).
// Quad-shfl logit reduce, wave softmax denom (*4), no max-sub. 4-wave blocks,
// LDS c*33+e reduce, f32 partials [b][32chunks].
// grid = (32 n-chunks of 64, BATCH), block 256.
// ---------------------------------------------------------------------------
__global__ __launch_bounds__(256)
void k3_sweep(const __hip_bfloat16* __restrict__ u, const float* __restrict__ V,
              float* __restrict__ part)
{
    __shared__ float red[4 * 2112];                  // [wave][c*33+e]
    const int t     = threadIdx.x;
    const int lane  = t & 63;
    const int wv    = t >> 6;
    const int chunk = blockIdx.x;
    const int b     = blockIdx.y;

    const int qr = lane >> 2;                        // 0..15: capsule-in-quarter
    const int es = (lane & 3) * 8;                   // e-slice start

    float vr[4][8];
    #pragma unroll
    for (int q = 0; q < 4; ++q) {
        const float* vp = V + (size_t)b * ROW + (q * 16 + qr) * DCAP + es;
        const float4 v0 = *(const float4*)(vp);
        const float4 v1 = *(const float4*)(vp + 4);
        vr[q][0]=v0.x; vr[q][1]=v0.y; vr[q][2]=v0.z; vr[q][3]=v0.w;
        vr[q][4]=v1.x; vr[q][5]=v1.y; vr[q][6]=v1.z; vr[q][7]=v1.w;
    }

    float sacc[4][8];
    #pragma unroll
    for (int q = 0; q < 4; ++q)
        #pragma unroll
        for (int j = 0; j < 8; ++j) sacc[q][j] = 0.f;

    const int nbase = chunk * 64 + wv * 16;
    // u row = n*BATCH + b ; per-n stride = BATCH*ROW
    const __hip_bfloat16* ubase = u + ((size_t)nbase * BATCH + b) * ROW + lane * 8;

    uint4 A[4];
    #pragma unroll
    for (int q = 0; q < 4; ++q)
        A[q] = *(const uint4*)(ubase + q * 512);

    for (int it = 0; it < 16; ++it) {
        uint4 Bn[4];
        if (it < 15) {
            const __hip_bfloat16* un = ubase + (size_t)(it + 1) * (BATCH * ROW);
            #pragma unroll
            for (int q = 0; q < 4; ++q)
                Bn[q] = *(const uint4*)(un + q * 512);
        }

        float p[4];
        #pragma unroll
        for (int q = 0; q < 4; ++q) {
            const uint32 w0 = A[q].x, w1 = A[q].y, w2 = A[q].z, w3 = A[q].w;
            float l0 = bf_lo(w0) * vr[q][0];
            float l1 = bf_hi(w0) * vr[q][1];
            l0 = fmaf(bf_lo(w1), vr[q][2], l0);
            l1 = fmaf(bf_hi(w1), vr[q][3], l1);
            l0 = fmaf(bf_lo(w2), vr[q][4], l0);
            l1 = fmaf(bf_hi(w2), vr[q][5], l1);
            l0 = fmaf(bf_lo(w3), vr[q][6], l0);
            l1 = fmaf(bf_hi(w3), vr[q][7], l1);
            p[q] = l0 + l1;
        }
        #pragma unroll
        for (int q = 0; q < 4; ++q) {
            p[q] += __shfl_xor(p[q], 1);
            p[q] += __shfl_xor(p[q], 2);
        }
        float e0 = __expf(p[0]), e1 = __expf(p[1]),
              e2 = __expf(p[2]), e3 = __expf(p[3]);
        float s = (e0 + e1) + (e2 + e3);
        s += __shfl_xor(s, 4);
        s += __shfl_xor(s, 8);
        s += __shfl_xor(s, 16);
        s += __shfl_xor(s, 32);                      // s = 4 * sum_c exp
        const float inv = 4.0f / s;
        const float cw[4] = {e0 * inv, e1 * inv, e2 * inv, e3 * inv};

        #pragma unroll
        for (int q = 0; q < 4; ++q) {
            const uint32 w0 = A[q].x, w1 = A[q].y, w2 = A[q].z, w3 = A[q].w;
            const float c = cw[q];
            sacc[q][0] = fmaf(c, bf_lo(w0), sacc[q][0]);
            sacc[q][1] = fmaf(c, bf_hi(w0), sacc[q][1]);
            sacc[q][2] = fmaf(c, bf_lo(w1), sacc[q][2]);
            sacc[q][3] = fmaf(c, bf_hi(w1), sacc[q][3]);
            sacc[q][4] = fmaf(c, bf_lo(w2), sacc[q][4]);
            sacc[q][5] = fmaf(c, bf_hi(w2), sacc[q][5]);
            sacc[q][6] = fmaf(c, bf_lo(w3), sacc[q][6]);
            sacc[q][7] = fmaf(c, bf_hi(w3), sacc[q][7]);
        }

        if (it < 15) {
            #pragma unroll
            for (int q = 0; q < 4; ++q) A[q] = Bn[q];
        }
    }

    #pragma unroll
    for (int q = 0; q < 4; ++q) {
        const int c = q * 16 + qr;
        #pragma unroll
        for (int j = 0; j < 8; ++j)
            red[wv * 2112 + c * 33 + es + j] = sacc[q][j];
    }
    __syncthreads();
    #pragma unroll
    for (int k = 0; k < 8; ++k) {
        const int pp = t + 256 * k;
        const int c = pp >> 5, e = pp & 31;
        part[((size_t)b * 32 + chunk) * ROW + pp] =
            red[0*2112 + c*33+e] + red[1*2112 + c*33+e] +
            red[2*2112 + c*33+e] + red[3*2112 + c*33+e];
    }
}

// ---------------------------------------------------------------------------
extern "C" void kernel_launch(void* const* d_in, const int* in_sizes, int n_in,
                              void* d_out, int out_size, void* d_ws, size_t ws_size,
                              hipStream_t stream)
{
    const float* x  = (const float*)d_in[0];
    const float* W  = (const float*)d_in[1];
    const float* Bc = (const float*)d_in[2];
    float* out = (float*)d_out;

    const size_t off_u    = 0;                       // u: 32*2048*2048 bf16 = 256 MiB
    const size_t off_part = 268435456;               // part: 32 MiB max
    const size_t off_V    = off_part + 33554432;     // V: 32*64*32 f32
    const size_t need     = off_V + 262144;
    if (ws_size < need) return;

    __hip_bfloat16* u  = (__hip_bfloat16*)((char*)d_ws + off_u);
    ushort* part_bf    = (ushort*)((char*)d_ws + off_part);
    float*  part_f     = (float*)((char*)d_ws + off_part);   // aliased: consumed before k3 writes
    float*  V          = (float*)((char*)d_ws + off_V);

    // iter 1: u + uniform-softmax s1 fused (bf16 partials)
    k1_predict<<<dim3(2, 256), 256, 0, stream>>>(x, W, Bc, u, part_bf);
    k2_squash <<<dim3(8, BATCH), 64, 0, stream>>>(part_bf, 256, 1, 1.0f/64.0f, V, nullptr, 1);
    // iter 2: logits = u.V (V=v1), softmax, s2
    k3_sweep  <<<dim3(32, BATCH), 256, 0, stream>>>(u, V, part_f);
    k2_squash <<<dim3(8, BATCH), 64, 0, stream>>>(part_f, 32, 0, 1.0f, V, nullptr, 0);
    // iter 3: logits = u.(v1+v2), softmax, s3 -> v3 = output
    k3_sweep  <<<dim3(32, BATCH), 256, 0, stream>>>(u, V, part_f);
    k2_squash <<<dim3(8, BATCH), 64, 0, stream>>>(part_f, 32, 0, 1.0f, V, out, 0);
}